// Round 5
// baseline (184.777 us; speedup 1.0000x reference)
//
#include <hip/hip_runtime.h>

#define IMG 224
#define PATCHSZ 16
#define CHN 3
#define DDIM 768
#define ROWN 14
#define NPATCH 196
#define PDIM 768
#define BATCH 32

#define DTILE 128                 // d-cols per block (6 blocks per patch)
#define NDBLK (DDIM / DTILE)      // 6
#define KCHUNK 64                 // P chunk rows
#define NCHUNK (PDIM / KCHUNK)    // 12
#define KSUB 16                   // W subchunk rows
#define NSUB (PDIM / KSUB)        // 48

// Kernel 1: x[32][3][224][224] -> P[196][32][768]
__global__ void extract_patches_kernel(const float* __restrict__ x,
                                       float* __restrict__ P) {
    int i = blockIdx.x * blockDim.x + threadIdx.x;
    if (i >= NPATCH * BATCH * PDIM) return;
    int k  = i % PDIM;
    int nb = i / PDIM;
    int b  = nb % BATCH;
    int n  = nb / BATCH;
    int ch = k >> 8;
    int py = (k >> 4) & 15;
    int px = k & 15;
    int r = n / ROWN, c = n % ROWN;
    P[i] = x[(((size_t)b * CHN + ch) * IMG + r * PATCHSZ + py) * IMG
             + c * PATCHSZ + px];
}

#define ACC_ROW(i, pv, wj)                                                   \
    acc[i][0] = fmaf(pv, wj.x, acc[i][0]);                                   \
    acc[i][1] = fmaf(pv, wj.y, acc[i][1]);                                   \
    acc[i][2] = fmaf(pv, wj.z, acc[i][2]);                                   \
    acc[i][3] = fmaf(pv, wj.w, acc[i][3]);

// per patch n: out[:,n,d0:d0+128] = P[n] (32x768) * W[n][:,d0:d0+128] + bias
// grid 196*6, block 256; thread tile 4 batches x 4 d-cols.
// W: global_load_lds double-buffer (zero VGPR round trip).
__global__ __launch_bounds__(256, 4) void patch_gemm_kernel(
    const float* __restrict__ P,    // [196][32][768]
    const float* __restrict__ W,    // [196][768][768]
    const float* __restrict__ bias, // [196][768]
    float* __restrict__ out)        // [32][196][768]
{
    __shared__ __align__(16) float wt[2][KSUB][DTILE];   // 16 KB W ping-pong
    __shared__ __align__(16) float ap[2][KCHUNK][BATCH]; // 16 KB P ping-pong

    const int blk  = blockIdx.x;
    const int n    = blk / NDBLK;
    const int dblk = blk % NDBLK;
    const int tid  = threadIdx.x;
    const int ln   = tid & 63;      // lane
    const int wv   = tid >> 6;      // wave 0..3
    const int dq   = ln & 31;       // d-quad 0..31
    const int b0   = (tid >> 5) * 4;// batch group (8 groups x 4 batches)
    const int d    = dblk * DTILE + dq * 4;

    const float* Wn0 = W + (size_t)n * PDIM * DDIM + dblk * DTILE;
    const float* Pn  = P + (size_t)n * BATCH * PDIM;

    // P staging mapping: thread -> (batch sb, 8 consecutive k at sk)
    const int sb = tid >> 3;          // 0..31
    const int sk = (tid & 7) * 8;     // 0..56

    float acc[4][4];
#pragma unroll
    for (int i = 0; i < 4; ++i)
#pragma unroll
        for (int j = 0; j < 4; ++j) acc[i][j] = 0.f;

    // issue one W subchunk (16 rows x 128 cols, 8 KB) into wt[u&1].
    // per wave: 2 x global_load_lds_dwordx4; each stages 2 rows (1KB).
    auto issueW = [&](int u) {
        const float* src = Wn0 + (size_t)u * KSUB * DDIM;
        float* dst = &wt[u & 1][0][0];
#pragma unroll
        for (int j = 0; j < 2; ++j) {
            const int row = wv * 4 + j * 2 + (ln >> 5);
            __builtin_amdgcn_global_load_lds(
                (const __attribute__((address_space(1))) unsigned int*)
                    (src + (size_t)row * DDIM + dq * 4),
                (__attribute__((address_space(3))) unsigned int*)
                    (dst + row * DTILE + dq * 4),
                16, 0, 0);
        }
    };

    // prologue: stage P chunk 0, prefetch P chunk 1, issue W subchunk 0
    {
        const float* s = Pn + (size_t)sb * PDIM + sk;
        float4 v0 = *reinterpret_cast<const float4*>(s);
        float4 v1 = *reinterpret_cast<const float4*>(s + 4);
        float (*apb)[BATCH] = ap[0];
        apb[sk + 0][sb] = v0.x; apb[sk + 1][sb] = v0.y;
        apb[sk + 2][sb] = v0.z; apb[sk + 3][sb] = v0.w;
        apb[sk + 4][sb] = v1.x; apb[sk + 5][sb] = v1.y;
        apb[sk + 6][sb] = v1.z; apb[sk + 7][sb] = v1.w;
    }
    float4 pn0, pn1;
    {
        const float* s = Pn + (size_t)sb * PDIM + KCHUNK + sk;
        pn0 = *reinterpret_cast<const float4*>(s);
        pn1 = *reinterpret_cast<const float4*>(s + 4);
    }
    issueW(0);

#pragma unroll 1
    for (int u = 0; u < NSUB; ++u) {
        __syncthreads();   // drains vmcnt+lgkmcnt: W(u) landed, P visible
        if (u + 1 < NSUB) issueW(u + 1);

        const int c  = u >> 2;          // P chunk index
        const int kb = (u & 3) * KSUB;  // k offset within P chunk
        const float* wbuf = &wt[u & 1][0][0] + dq * 4;
        const float* pbuf = &ap[c & 1][0][0] + b0;

#pragma unroll 4
        for (int kk = 0; kk < KSUB; ++kk) {
            float4 w = *reinterpret_cast<const float4*>(wbuf + kk * DTILE);
            float4 p = *reinterpret_cast<const float4*>(
                pbuf + (size_t)(kb + kk) * BATCH);
            ACC_ROW(0, p.x, w) ACC_ROW(1, p.y, w)
            ACC_ROW(2, p.z, w) ACC_ROW(3, p.w, w)
        }

        // at the last subchunk of chunk c: stage P chunk c+1, prefetch c+2
        if ((u & 3) == 3 && c + 1 < NCHUNK) {
            float (*apb)[BATCH] = ap[(c + 1) & 1];
            apb[sk + 0][sb] = pn0.x; apb[sk + 1][sb] = pn0.y;
            apb[sk + 2][sb] = pn0.z; apb[sk + 3][sb] = pn0.w;
            apb[sk + 4][sb] = pn1.x; apb[sk + 5][sb] = pn1.y;
            apb[sk + 6][sb] = pn1.z; apb[sk + 7][sb] = pn1.w;
            if (c + 2 < NCHUNK) {
                const float* s = Pn + (size_t)sb * PDIM + (c + 2) * KCHUNK + sk;
                pn0 = *reinterpret_cast<const float4*>(s);
                pn1 = *reinterpret_cast<const float4*>(s + 4);
            }
        }
    }

    float4 bv = *reinterpret_cast<const float4*>(bias + (size_t)n * DDIM + d);
#pragma unroll
    for (int i = 0; i < 4; ++i) {
        const int b = b0 + i;
        float4 o;
        o.x = acc[i][0] + bv.x;
        o.y = acc[i][1] + bv.y;
        o.z = acc[i][2] + bv.z;
        o.w = acc[i][3] + bv.w;
        *reinterpret_cast<float4*>(out + ((size_t)b * NPATCH + n) * DDIM + d) = o;
    }
}

extern "C" void kernel_launch(void* const* d_in, const int* in_sizes, int n_in,
                              void* d_out, int out_size, void* d_ws, size_t ws_size,
                              hipStream_t stream) {
    const float* x    = (const float*)d_in[0];
    const float* W    = (const float*)d_in[1];
    const float* bias = (const float*)d_in[2];
    float* out = (float*)d_out;
    float* P   = (float*)d_ws;   // 196*32*768*4 = 19.3 MB

    int total = NPATCH * BATCH * PDIM;
    extract_patches_kernel<<<(total + 255) / 256, 256, 0, stream>>>(x, P);
    patch_gemm_kernel<<<NPATCH * NDBLK, 256, 0, stream>>>(P, W, bias, out);
}

// Round 6
// 178.987 us; speedup vs baseline: 1.0323x; 1.0323x over previous
//
#include <hip/hip_runtime.h>

#define IMG 224
#define PATCHSZ 16
#define CHN 3
#define DDIM 768
#define ROWN 14
#define NPATCH 196
#define PDIM 768
#define BATCH 32

#define DTILE 256                 // d-cols per block (3 blocks per patch)
#define NDBLK (DDIM / DTILE)      // 3
#define KCHUNK 64                 // P chunk rows
#define NCHUNK (PDIM / KCHUNK)    // 12
#define KSUB 32                   // W subchunk rows
#define NSUB (PDIM / KSUB)        // 24

#define ACC_ROW(i, pv, wj)                                                   \
    acc[i][0] = fmaf(pv, wj.x, acc[i][0]);                                   \
    acc[i][1] = fmaf(pv, wj.y, acc[i][1]);                                   \
    acc[i][2] = fmaf(pv, wj.z, acc[i][2]);                                   \
    acc[i][3] = fmaf(pv, wj.w, acc[i][3]);

// Fused: per patch n: out[:,n,d0:d0+256] = patches(x)[n] (32x768) *
//        W[n][:,d0:d0+256] + bias.  grid 196*3, block 256 (4 waves);
// thread tile 8 batches x 4 d-cols. W: global_load_lds double-buffer.
__global__ __launch_bounds__(256, 2) void patch_gemm_kernel(
    const float* __restrict__ x,    // [32][3][224][224]
    const float* __restrict__ W,    // [196][768][768]
    const float* __restrict__ bias, // [196][768]
    float* __restrict__ out)        // [32][196][768]
{
    __shared__ __align__(16) float wt[2][KSUB][DTILE];   // 64 KB W ping-pong
    __shared__ __align__(16) float ap[2][KCHUNK][BATCH]; // 16 KB P ping-pong

    const int blk  = blockIdx.x;
    const int n    = blk / NDBLK;
    const int dblk = blk % NDBLK;
    const int tid  = threadIdx.x;
    const int ln   = tid & 63;      // lane; d-quad index (64 x 4 = 256 cols)
    const int wv   = tid >> 6;      // wave 0..3
    const int b0   = wv * 8;        // batch group per wave
    const int d    = dblk * DTILE + ln * 4;

    const float* Wn0 = W + (size_t)n * PDIM * DDIM + dblk * DTILE;

    // P staging mapping: thread -> (batch sb, 8 consecutive k at sk)
    const int sb = tid >> 3;          // 0..31
    const int sk = (tid & 7) * 8;     // 0..56
    const int rr = n / ROWN, cc = n % ROWN;

    // x source for P chunk c: k0 = c*64 + sk; 8 consecutive k lie in one
    // contiguous 32B row segment of x (px in {0,8}).
    auto xsrc = [&](int c) {
        int k0 = c * KCHUNK + sk;
        int ch = k0 >> 8;
        int py = (k0 >> 4) & 15;
        int px = k0 & 15;
        return x + (((size_t)sb * CHN + ch) * IMG + (rr * PATCHSZ + py)) * IMG
                 + cc * PATCHSZ + px;
    };

    float acc[8][4];
#pragma unroll
    for (int i = 0; i < 8; ++i)
#pragma unroll
        for (int j = 0; j < 4; ++j) acc[i][j] = 0.f;

    // issue one W subchunk (32 rows x 256 cols, 32 KB) into wt[u&1].
    // per wave: 8 x global_load_lds_dwordx4, one 1KB row each.
    auto issueW = [&](int u) {
        const float* src = Wn0 + (size_t)u * KSUB * DDIM;
        float* dst = &wt[u & 1][0][0];
#pragma unroll
        for (int j = 0; j < 8; ++j) {
            const int row = wv * 8 + j;
            __builtin_amdgcn_global_load_lds(
                (const __attribute__((address_space(1))) unsigned int*)
                    (src + (size_t)row * DDIM + ln * 4),
                (__attribute__((address_space(3))) unsigned int*)
                    (dst + row * DTILE + ln * 4),
                16, 0, 0);
        }
    };

    // prologue: stage P chunk 0 from x, prefetch chunk 1, issue W subchunk 0
    {
        const float* xs = xsrc(0);
        float4 v0 = *reinterpret_cast<const float4*>(xs);
        float4 v1 = *reinterpret_cast<const float4*>(xs + 4);
        float (*apb)[BATCH] = ap[0];
        apb[sk + 0][sb] = v0.x; apb[sk + 1][sb] = v0.y;
        apb[sk + 2][sb] = v0.z; apb[sk + 3][sb] = v0.w;
        apb[sk + 4][sb] = v1.x; apb[sk + 5][sb] = v1.y;
        apb[sk + 6][sb] = v1.z; apb[sk + 7][sb] = v1.w;
    }
    float4 pn0, pn1;
    {
        const float* xs = xsrc(1);
        pn0 = *reinterpret_cast<const float4*>(xs);
        pn1 = *reinterpret_cast<const float4*>(xs + 4);
    }
    issueW(0);

#pragma unroll 1
    for (int u = 0; u < NSUB; ++u) {
        __syncthreads();   // drains vmcnt+lgkmcnt: W(u) landed, P visible
        if (u + 1 < NSUB) issueW(u + 1);

        const int c  = u >> 1;          // P chunk index (2 subchunks/chunk)
        const int kb = (u & 1) * KSUB;  // k offset within P chunk
        const float* wbuf = &wt[u & 1][0][0] + ln * 4;
        const float* pbuf = &ap[c & 1][0][0] + b0;

#pragma unroll 4
        for (int kk = 0; kk < KSUB; ++kk) {
            float4 w = *reinterpret_cast<const float4*>(wbuf + kk * DTILE);
            const float* pp = pbuf + (size_t)(kb + kk) * BATCH;
            float4 p01 = *reinterpret_cast<const float4*>(pp);
            float4 p23 = *reinterpret_cast<const float4*>(pp + 4);
            ACC_ROW(0, p01.x, w) ACC_ROW(1, p01.y, w)
            ACC_ROW(2, p01.z, w) ACC_ROW(3, p01.w, w)
            ACC_ROW(4, p23.x, w) ACC_ROW(5, p23.y, w)
            ACC_ROW(6, p23.z, w) ACC_ROW(7, p23.w, w)
        }

        // at the last subchunk of chunk c: stage P chunk c+1, prefetch c+2
        if ((u & 1) == 1 && c + 1 < NCHUNK) {
            float (*apb)[BATCH] = ap[(c + 1) & 1];
            apb[sk + 0][sb] = pn0.x; apb[sk + 1][sb] = pn0.y;
            apb[sk + 2][sb] = pn0.z; apb[sk + 3][sb] = pn0.w;
            apb[sk + 4][sb] = pn1.x; apb[sk + 5][sb] = pn1.y;
            apb[sk + 6][sb] = pn1.z; apb[sk + 7][sb] = pn1.w;
            if (c + 2 < NCHUNK) {
                const float* xs = xsrc(c + 2);
                pn0 = *reinterpret_cast<const float4*>(xs);
                pn1 = *reinterpret_cast<const float4*>(xs + 4);
            }
        }
    }

    float4 bv = *reinterpret_cast<const float4*>(bias + (size_t)n * DDIM + d);
#pragma unroll
    for (int i = 0; i < 8; ++i) {
        const int b = b0 + i;
        float4 o;
        o.x = acc[i][0] + bv.x;
        o.y = acc[i][1] + bv.y;
        o.z = acc[i][2] + bv.z;
        o.w = acc[i][3] + bv.w;
        *reinterpret_cast<float4*>(out + ((size_t)b * NPATCH + n) * DDIM + d) = o;
    }
}

extern "C" void kernel_launch(void* const* d_in, const int* in_sizes, int n_in,
                              void* d_out, int out_size, void* d_ws, size_t ws_size,
                              hipStream_t stream) {
    const float* x    = (const float*)d_in[0];
    const float* W    = (const float*)d_in[1];
    const float* bias = (const float*)d_in[2];
    float* out = (float*)d_out;

    patch_gemm_kernel<<<NPATCH * NDBLK, 256, 0, stream>>>(x, W, bias, out);
}